// Round 1
// baseline (621.364 us; speedup 1.0000x reference)
//
#include <hip/hip_runtime.h>
#include <math.h>

// Problem constants
#define BDIM 4
#define GDIM 40
#define CDIM 13
#define TDIM 1024
#define FDIM 513                 // T/2 + 1
#define BG   (BDIM*GDIM)         // 160
#define NROW (BG*FDIM)           // 82080 rows of [13] complex
#define NCHUNK 15
#define ROWS_PER_CHUNK 36        // 15*36 = 540 >= 513
#define JMAX 9                   // ceil(513/64)

__device__ __forceinline__ unsigned bitrev10(unsigned x) { return __brev(x) >> 22; }

// ---------------- Kernel 1: rfft(1024) per (b,g,c) signal ----------------
// out layout: xf[(bg*F + f)*C + c]  (complex float2)
__global__ void fft_fwd(const float* __restrict__ x, float2* __restrict__ xf) {
    __shared__ float re[1024], im[1024];
    const int sig = blockIdx.x;                  // bg*13 + c
    const float* xin = x + (size_t)sig * TDIM;
    for (int t = threadIdx.x; t < 1024; t += blockDim.x) {
        unsigned r = bitrev10(t);
        re[r] = xin[t];
        im[r] = 0.f;
    }
    __syncthreads();
    for (int s = 0; s < 10; ++s) {
        int half = 1 << s;
        for (int j = threadIdx.x; j < 512; j += blockDim.x) {
            int grp = j >> s;
            int pos = j & (half - 1);
            int i1 = (grp << (s + 1)) + pos;
            int i2 = i1 + half;
            float ang = -(float)M_PI * (float)pos / (float)half;
            float sw, cw; __sincosf(ang, &sw, &cw);
            float xr = re[i2], xi = im[i2];
            float tr = cw * xr - sw * xi;
            float ti = cw * xi + sw * xr;
            float ur = re[i1], ui = im[i1];
            re[i1] = ur + tr; im[i1] = ui + ti;
            re[i2] = ur - tr; im[i2] = ui - ti;
        }
        __syncthreads();
    }
    const int bg = sig / CDIM, c = sig % CDIM;
    for (int f = threadIdx.x; f < FDIM; f += blockDim.x) {
        xf[((size_t)bg * FDIM + f) * CDIM + c] = make_float2(re[f], im[f]);
    }
}

// ---------------- Kernel 2: Q/K/V = Xrow @ W (13x13, real weights) ----------------
__global__ void qkv_kernel(const float2* __restrict__ xf,
                           const float* __restrict__ wq,
                           const float* __restrict__ wk,
                           const float* __restrict__ wv,
                           float2* __restrict__ q, float2* __restrict__ k,
                           float2* __restrict__ v) {
    int gid = blockIdx.x * blockDim.x + threadIdx.x;
    if (gid >= NROW * CDIM) return;
    int r = gid / CDIM;
    int i = gid - r * CDIM;
    const float2* xrow = xf + (size_t)r * CDIM;
    float qr = 0, qi = 0, kr = 0, ki = 0, vr = 0, vi = 0;
#pragma unroll
    for (int c = 0; c < CDIM; ++c) {
        float2 xc = xrow[c];
        float a = wq[c * CDIM + i]; qr += xc.x * a; qi += xc.y * a;
        float b = wk[c * CDIM + i]; kr += xc.x * b; ki += xc.y * b;
        float d = wv[c * CDIM + i]; vr += xc.x * d; vi += xc.y * d;
    }
    q[gid] = make_float2(qr, qi);
    k[gid] = make_float2(kr, ki);
    v[gid] = make_float2(vr, vi);
}

// ---------------- Kernel 3: attention per (b,g); one wave per Q-row ----------------
// scores[f,f2] = | sum_c q[f,c]*k[f2,c] |  (complex product, no conj)
// out_spec[(bg*C + c)*F + f] = sum_f2 softmax(scores)[f,f2] * v[f2,c]
__global__ __launch_bounds__(256) void attn_kernel(const float2* __restrict__ q,
                                                   const float2* __restrict__ k,
                                                   const float2* __restrict__ v,
                                                   float2* __restrict__ outspec) {
    __shared__ float2 Ks[FDIM * CDIM];           // 53352 B
    const int bg = blockIdx.x / NCHUNK;
    const int chunk = blockIdx.x % NCHUNK;
    const size_t base = (size_t)bg * FDIM * CDIM;
    for (int idx = threadIdx.x; idx < FDIM * CDIM; idx += blockDim.x)
        Ks[idx] = k[base + idx];
    __syncthreads();

    const int wave = threadIdx.x >> 6;
    const int lane = threadIdx.x & 63;
    const int rows_per_wave = ROWS_PER_CHUNK / 4; // 9

    for (int rr = 0; rr < rows_per_wave; ++rr) {
        int f = chunk * ROWS_PER_CHUNK + wave * rows_per_wave + rr;
        if (f >= FDIM) continue;                  // wave-uniform
        const float2* qrow = q + base + (size_t)f * CDIM;
        float qre[CDIM], qim[CDIM];
#pragma unroll
        for (int c = 0; c < CDIM; ++c) { float2 t = qrow[c]; qre[c] = t.x; qim[c] = t.y; }

        float s[JMAX];
        float m = -INFINITY;
#pragma unroll
        for (int j = 0; j < JMAX; ++j) {
            int f2 = lane + 64 * j;
            if (f2 < FDIM) {
                float sr = 0.f, si = 0.f;
                const float2* krow = &Ks[f2 * CDIM];
#pragma unroll
                for (int c = 0; c < CDIM; ++c) {
                    float2 kc = krow[c];
                    sr += qre[c] * kc.x - qim[c] * kc.y;
                    si += qre[c] * kc.y + qim[c] * kc.x;
                }
                s[j] = sqrtf(sr * sr + si * si);
                m = fmaxf(m, s[j]);
            } else {
                s[j] = -INFINITY;
            }
        }
#pragma unroll
        for (int off = 32; off >= 1; off >>= 1)
            m = fmaxf(m, __shfl_xor(m, off));

        float p[JMAX]; float l = 0.f;
#pragma unroll
        for (int j = 0; j < JMAX; ++j) {
            p[j] = (lane + 64 * j < FDIM) ? __expf(s[j] - m) : 0.f;
            l += p[j];
        }
#pragma unroll
        for (int off = 32; off >= 1; off >>= 1)
            l += __shfl_xor(l, off);
        float inv = 1.f / l;

        float ar[CDIM], ai[CDIM];
#pragma unroll
        for (int c = 0; c < CDIM; ++c) { ar[c] = 0.f; ai[c] = 0.f; }
#pragma unroll
        for (int j = 0; j < JMAX; ++j) {
            int f2 = lane + 64 * j;
            if (f2 < FDIM) {
                float w = p[j] * inv;
                const float2* vrow = v + base + (size_t)f2 * CDIM;
#pragma unroll
                for (int c = 0; c < CDIM; ++c) {
                    float2 vc = vrow[c];
                    ar[c] += w * vc.x;
                    ai[c] += w * vc.y;
                }
            }
        }
#pragma unroll
        for (int off = 32; off >= 1; off >>= 1) {
#pragma unroll
            for (int c = 0; c < CDIM; ++c) {
                ar[c] += __shfl_xor(ar[c], off);
                ai[c] += __shfl_xor(ai[c], off);
            }
        }
        if (lane == 0) {
#pragma unroll
            for (int c = 0; c < CDIM; ++c)
                outspec[((size_t)(bg * CDIM + c)) * FDIM + f] = make_float2(ar[c], ai[c]);
        }
    }
}

// ---------------- Kernel 4: irfft(1024) per (b,g,c) ----------------
// Build Hermitian 1024-bin spectrum, inverse FFT, take real part / 1024.
__global__ void fft_inv(const float2* __restrict__ spec, float* __restrict__ out) {
    __shared__ float re[1024], im[1024];
    const float2* S = spec + (size_t)blockIdx.x * FDIM;
    for (int t = threadIdx.x; t < 1024; t += blockDim.x) {
        int f = (t <= 512) ? t : 1024 - t;
        float2 sv = S[f];
        float sim = (t <= 512) ? sv.y : -sv.y;
        unsigned r = bitrev10(t);
        re[r] = sv.x;
        im[r] = sim;
    }
    __syncthreads();
    for (int s = 0; s < 10; ++s) {
        int half = 1 << s;
        for (int j = threadIdx.x; j < 512; j += blockDim.x) {
            int grp = j >> s;
            int pos = j & (half - 1);
            int i1 = (grp << (s + 1)) + pos;
            int i2 = i1 + half;
            float ang = (float)M_PI * (float)pos / (float)half;   // +sign = inverse
            float sw, cw; __sincosf(ang, &sw, &cw);
            float xr = re[i2], xi = im[i2];
            float tr = cw * xr - sw * xi;
            float ti = cw * xi + sw * xr;
            float ur = re[i1], ui = im[i1];
            re[i1] = ur + tr; im[i1] = ui + ti;
            re[i2] = ur - tr; im[i2] = ui - ti;
        }
        __syncthreads();
    }
    const float scale = 1.0f / 1024.0f;
    for (int t = threadIdx.x; t < 1024; t += blockDim.x)
        out[(size_t)blockIdx.x * TDIM + t] = re[t] * scale;
}

extern "C" void kernel_launch(void* const* d_in, const int* in_sizes, int n_in,
                              void* d_out, int out_size, void* d_ws, size_t ws_size,
                              hipStream_t stream) {
    const float* x  = (const float*)d_in[0];
    const float* wq = (const float*)d_in[1];
    const float* wk = (const float*)d_in[2];
    const float* wv = (const float*)d_in[3];
    float* out = (float*)d_out;

    const size_t n = (size_t)NROW * CDIM;        // 1,067,040 complex per buffer
    float2* xf = (float2*)d_ws;                  // x_fft, later reused as out-spectrum
    float2* q  = xf + n;
    float2* k  = q + n;
    float2* v  = k + n;

    fft_fwd<<<BG * CDIM, 256, 0, stream>>>(x, xf);
    qkv_kernel<<<(NROW * CDIM + 255) / 256, 256, 0, stream>>>(xf, wq, wk, wv, q, k, v);
    attn_kernel<<<BG * NCHUNK, 256, 0, stream>>>(q, k, v, xf /* outspec, aliases xf */);
    fft_inv<<<BG * CDIM, 256, 0, stream>>>(xf, out);
}

// Round 2
// 588.921 us; speedup vs baseline: 1.0551x; 1.0551x over previous
//
#include <hip/hip_runtime.h>
#include <math.h>

// Problem constants
#define BDIM 4
#define GDIM 40
#define CDIM 13
#define TDIM 1024
#define FDIM 513                 // T/2 + 1
#define BG   (BDIM*GDIM)         // 160
#define NROW (BG*FDIM)           // 82080 rows of [13] complex
#define WPB  9                   // waves (64-row chunks) per bg: 9*64=576 >= 513

__device__ __forceinline__ unsigned bitrev10(unsigned x) { return __brev(x) >> 22; }

// ---------------- Kernel 1: rfft(1024) per (b,g,c) signal ----------------
// out layout: xf[(bg*F + f)*C + c]  (complex float2)
__global__ void fft_fwd(const float* __restrict__ x, float2* __restrict__ xf) {
    __shared__ float re[1024], im[1024];
    const int sig = blockIdx.x;                  // bg*13 + c
    const float* xin = x + (size_t)sig * TDIM;
    for (int t = threadIdx.x; t < 1024; t += blockDim.x) {
        unsigned r = bitrev10(t);
        re[r] = xin[t];
        im[r] = 0.f;
    }
    __syncthreads();
    for (int s = 0; s < 10; ++s) {
        int half = 1 << s;
        for (int j = threadIdx.x; j < 512; j += blockDim.x) {
            int grp = j >> s;
            int pos = j & (half - 1);
            int i1 = (grp << (s + 1)) + pos;
            int i2 = i1 + half;
            float ang = -(float)M_PI * (float)pos / (float)half;
            float sw, cw; __sincosf(ang, &sw, &cw);
            float xr = re[i2], xi = im[i2];
            float tr = cw * xr - sw * xi;
            float ti = cw * xi + sw * xr;
            float ur = re[i1], ui = im[i1];
            re[i1] = ur + tr; im[i1] = ui + ti;
            re[i2] = ur - tr; im[i2] = ui - ti;
        }
        __syncthreads();
    }
    const int bg = sig / CDIM, c = sig % CDIM;
    for (int f = threadIdx.x; f < FDIM; f += blockDim.x) {
        xf[((size_t)bg * FDIM + f) * CDIM + c] = make_float2(re[f], im[f]);
    }
}

// ---------------- Kernel 2: Q/K/V = Xrow @ W (13x13, real weights) ----------------
__global__ void qkv_kernel(const float2* __restrict__ xf,
                           const float* __restrict__ wq,
                           const float* __restrict__ wk,
                           const float* __restrict__ wv,
                           float2* __restrict__ q, float2* __restrict__ k,
                           float2* __restrict__ v) {
    int gid = blockIdx.x * blockDim.x + threadIdx.x;
    if (gid >= NROW * CDIM) return;
    int r = gid / CDIM;
    int i = gid - r * CDIM;
    const float2* xrow = xf + (size_t)r * CDIM;
    float qr = 0, qi = 0, kr = 0, ki = 0, vr = 0, vi = 0;
#pragma unroll
    for (int c = 0; c < CDIM; ++c) {
        float2 xc = xrow[c];
        float a = wq[c * CDIM + i]; qr += xc.x * a; qi += xc.y * a;
        float b = wk[c * CDIM + i]; kr += xc.x * b; ki += xc.y * b;
        float d = wv[c * CDIM + i]; vr += xc.x * d; vi += xc.y * d;
    }
    q[gid] = make_float2(qr, qi);
    k[gid] = make_float2(kr, ki);
    v[gid] = make_float2(vr, vi);
}

// ---------------- Kernel 3: flash-style attention, one lane per Q-row ----------------
// Lanes of a wave own 64 consecutive Q-rows of one (b,g); the f2 loop is
// wave-uniform, so K-row/V-row loads are scalar (L2-broadcast) — zero LDS,
// zero cross-lane reduction. Online softmax per lane.
__global__ __launch_bounds__(64) void attn_kernel(const float2* __restrict__ q,
                                                  const float2* __restrict__ k,
                                                  const float2* __restrict__ v,
                                                  float2* __restrict__ outspec) {
    const int bg = blockIdx.x / WPB;
    const int w  = blockIdx.x % WPB;
    const int f  = w * 64 + threadIdx.x;         // this lane's Q-row
    const size_t base = (size_t)bg * FDIM * CDIM;
    const bool active = (f < FDIM);

    float qre[CDIM], qim[CDIM];
    {
        const float2* qrow = q + base + (size_t)(active ? f : 0) * CDIM;
#pragma unroll
        for (int c = 0; c < CDIM; ++c) { float2 t = qrow[c]; qre[c] = t.x; qim[c] = t.y; }
    }

    float ar[CDIM], ai[CDIM];
#pragma unroll
    for (int c = 0; c < CDIM; ++c) { ar[c] = 0.f; ai[c] = 0.f; }
    float m = -INFINITY, l = 0.f;

    const float2* __restrict__ kbase = k + base;
    const float2* __restrict__ vbase = v + base;

#pragma unroll 2
    for (int f2 = 0; f2 < FDIM; ++f2) {
        const float2* __restrict__ Krow = kbase + (size_t)f2 * CDIM;
        const float2* __restrict__ Vrow = vbase + (size_t)f2 * CDIM;
        float sr = 0.f, si = 0.f;
#pragma unroll
        for (int c = 0; c < CDIM; ++c) {
            float2 kc = Krow[c];
            sr = fmaf(qre[c], kc.x, sr);
            sr = fmaf(-qim[c], kc.y, sr);
            si = fmaf(qre[c], kc.y, si);
            si = fmaf(qim[c], kc.x, si);
        }
        float s = sqrtf(fmaf(sr, sr, si * si));
        if (s > m) {                              // rare after warm-up
            float alpha = __expf(m - s);          // exp(-inf)=0 handles first iter
            l *= alpha;
#pragma unroll
            for (int c = 0; c < CDIM; ++c) { ar[c] *= alpha; ai[c] *= alpha; }
            m = s;
        }
        float p = __expf(s - m);
        l += p;
#pragma unroll
        for (int c = 0; c < CDIM; ++c) {
            float2 vc = Vrow[c];
            ar[c] = fmaf(p, vc.x, ar[c]);
            ai[c] = fmaf(p, vc.y, ai[c]);
        }
    }

    if (active) {
        float inv = 1.f / l;
#pragma unroll
        for (int c = 0; c < CDIM; ++c)
            outspec[((size_t)(bg * CDIM + c)) * FDIM + f] =
                make_float2(ar[c] * inv, ai[c] * inv);
    }
}

// ---------------- Kernel 4: irfft(1024) per (b,g,c) ----------------
// Build Hermitian 1024-bin spectrum, inverse FFT, take real part / 1024.
__global__ void fft_inv(const float2* __restrict__ spec, float* __restrict__ out) {
    __shared__ float re[1024], im[1024];
    const float2* S = spec + (size_t)blockIdx.x * FDIM;
    for (int t = threadIdx.x; t < 1024; t += blockDim.x) {
        int f = (t <= 512) ? t : 1024 - t;
        float2 sv = S[f];
        float sim = (t <= 512) ? sv.y : -sv.y;
        unsigned r = bitrev10(t);
        re[r] = sv.x;
        im[r] = sim;
    }
    __syncthreads();
    for (int s = 0; s < 10; ++s) {
        int half = 1 << s;
        for (int j = threadIdx.x; j < 512; j += blockDim.x) {
            int grp = j >> s;
            int pos = j & (half - 1);
            int i1 = (grp << (s + 1)) + pos;
            int i2 = i1 + half;
            float ang = (float)M_PI * (float)pos / (float)half;   // +sign = inverse
            float sw, cw; __sincosf(ang, &sw, &cw);
            float xr = re[i2], xi = im[i2];
            float tr = cw * xr - sw * xi;
            float ti = cw * xi + sw * xr;
            float ur = re[i1], ui = im[i1];
            re[i1] = ur + tr; im[i1] = ui + ti;
            re[i2] = ur - tr; im[i2] = ui - ti;
        }
        __syncthreads();
    }
    const float scale = 1.0f / 1024.0f;
    for (int t = threadIdx.x; t < 1024; t += blockDim.x)
        out[(size_t)blockIdx.x * TDIM + t] = re[t] * scale;
}

extern "C" void kernel_launch(void* const* d_in, const int* in_sizes, int n_in,
                              void* d_out, int out_size, void* d_ws, size_t ws_size,
                              hipStream_t stream) {
    const float* x  = (const float*)d_in[0];
    const float* wq = (const float*)d_in[1];
    const float* wk = (const float*)d_in[2];
    const float* wv = (const float*)d_in[3];
    float* out = (float*)d_out;

    const size_t n = (size_t)NROW * CDIM;        // 1,067,040 complex per buffer
    float2* xf = (float2*)d_ws;                  // x_fft, later reused as out-spectrum
    float2* q  = xf + n;
    float2* k  = q + n;
    float2* v  = k + n;

    fft_fwd<<<BG * CDIM, 256, 0, stream>>>(x, xf);
    qkv_kernel<<<(NROW * CDIM + 255) / 256, 256, 0, stream>>>(xf, wq, wk, wv, q, k, v);
    attn_kernel<<<BG * WPB, 64, 0, stream>>>(q, k, v, xf /* outspec, aliases xf */);
    fft_inv<<<BG * CDIM, 256, 0, stream>>>(xf, out);
}

// Round 3
// 280.678 us; speedup vs baseline: 2.2138x; 2.0982x over previous
//
#include <hip/hip_runtime.h>
#include <math.h>

// Problem constants
#define BDIM 4
#define GDIM 40
#define CDIM 13
#define TDIM 1024
#define FDIM 513                 // T/2 + 1
#define BG   (BDIM*GDIM)         // 160
#define NROW (BG*FDIM)           // 82080 rows of [13] complex
#define NCHUNK 9                 // 9*64 = 576 >= 513 row-chunks per bg
#define TILE 64                  // f2 rows staged per LDS tile
#define NWAVE 4                  // waves per block; f2 split 4 ways
#define KSTRIDE 28               // floats per LDS tile row (26 padded to 28 for float4)
#define MSTRIDE 29               // floats per merge-buffer row (28 padded to 29)

__device__ __forceinline__ unsigned bitrev10(unsigned x) { return __brev(x) >> 22; }

// ---------------- Kernel 1: rfft(1024) per (b,g,c) signal ----------------
// out layout: xf[(bg*F + f)*C + c]  (complex float2)
__global__ void fft_fwd(const float* __restrict__ x, float2* __restrict__ xf) {
    __shared__ float re[1024], im[1024];
    const int sig = blockIdx.x;                  // bg*13 + c
    const float* xin = x + (size_t)sig * TDIM;
    for (int t = threadIdx.x; t < 1024; t += blockDim.x) {
        unsigned r = bitrev10(t);
        re[r] = xin[t];
        im[r] = 0.f;
    }
    __syncthreads();
    for (int s = 0; s < 10; ++s) {
        int half = 1 << s;
        for (int j = threadIdx.x; j < 512; j += blockDim.x) {
            int grp = j >> s;
            int pos = j & (half - 1);
            int i1 = (grp << (s + 1)) + pos;
            int i2 = i1 + half;
            float ang = -(float)M_PI * (float)pos / (float)half;
            float sw, cw; __sincosf(ang, &sw, &cw);
            float xr = re[i2], xi = im[i2];
            float tr = cw * xr - sw * xi;
            float ti = cw * xi + sw * xr;
            float ur = re[i1], ui = im[i1];
            re[i1] = ur + tr; im[i1] = ui + ti;
            re[i2] = ur - tr; im[i2] = ui - ti;
        }
        __syncthreads();
    }
    const int bg = sig / CDIM, c = sig % CDIM;
    for (int f = threadIdx.x; f < FDIM; f += blockDim.x) {
        xf[((size_t)bg * FDIM + f) * CDIM + c] = make_float2(re[f], im[f]);
    }
}

// ---------------- Kernel 2: Q/K/V = Xrow @ W (13x13, real weights) ----------------
__global__ void qkv_kernel(const float2* __restrict__ xf,
                           const float* __restrict__ wq,
                           const float* __restrict__ wk,
                           const float* __restrict__ wv,
                           float2* __restrict__ q, float2* __restrict__ k,
                           float2* __restrict__ v) {
    int gid = blockIdx.x * blockDim.x + threadIdx.x;
    if (gid >= NROW * CDIM) return;
    int r = gid / CDIM;
    int i = gid - r * CDIM;
    const float2* xrow = xf + (size_t)r * CDIM;
    float qr = 0, qi = 0, kr = 0, ki = 0, vr = 0, vi = 0;
#pragma unroll
    for (int c = 0; c < CDIM; ++c) {
        float2 xc = xrow[c];
        float a = wq[c * CDIM + i]; qr += xc.x * a; qi += xc.y * a;
        float b = wk[c * CDIM + i]; kr += xc.x * b; ki += xc.y * b;
        float d = wv[c * CDIM + i]; vr += xc.x * d; vi += xc.y * d;
    }
    q[gid] = make_float2(qr, qi);
    k[gid] = make_float2(kr, ki);
    v[gid] = make_float2(vr, vi);
}

// ---------------- Kernel 3: attention ----------------
// Block = 256 threads = 4 waves, covering 64 Q-rows of one (b,g).
// Lane (tid&63) owns Q-row chunk*64+lane; wave w handles f2 = {w, w+4, w+8, ...}
// (a partition of the f2 axis), each maintaining an online-softmax partial
// (m,l,acc[26]). K/V tiles staged in LDS (padded stride 28); inner-loop reads
// are wave-uniform -> LDS broadcast, conflict-free. Partials merged via LDS.
__global__ __launch_bounds__(256) void attn_kernel(const float2* __restrict__ q,
                                                   const float2* __restrict__ k,
                                                   const float2* __restrict__ v,
                                                   float2* __restrict__ outspec) {
    __shared__ __align__(16) float Kt[TILE * KSTRIDE];       // 7168 B
    __shared__ __align__(16) float Vt[TILE * KSTRIDE];       // 7168 B
    __shared__ float Mbuf[(NWAVE - 1) * 64 * MSTRIDE];       // 22272 B

    const int bg    = blockIdx.x / NCHUNK;
    const int chunk = blockIdx.x % NCHUNK;
    const int tid   = threadIdx.x;
    const int w     = tid >> 6;
    const int lane  = tid & 63;
    const int frow  = chunk * 64 + lane;
    const bool writer = (frow < FDIM);
    const int f     = writer ? frow : (FDIM - 1);
    const size_t base = (size_t)bg * FDIM * CDIM;

    float qre[CDIM], qim[CDIM];
    {
        const float2* qrow = q + base + (size_t)f * CDIM;
#pragma unroll
        for (int c = 0; c < CDIM; ++c) { float2 t = qrow[c]; qre[c] = t.x; qim[c] = t.y; }
    }

    float ar[CDIM], ai[CDIM];
#pragma unroll
    for (int c = 0; c < CDIM; ++c) { ar[c] = 0.f; ai[c] = 0.f; }
    float m = -INFINITY, l = 0.f;

    const float2* __restrict__ kg = k + base;   // rows of 13 float2
    const float2* __restrict__ vg = v + base;

    for (int t0 = 0; t0 < FDIM; t0 += TILE) {
        const int tl = min(TILE, FDIM - t0);
        __syncthreads();                         // previous tile fully consumed
        // stage K/V tile as float2 (tl*13 each)
        const int nd2 = tl * CDIM;
        for (int idx = tid; idx < nd2; idx += 256) {
            int r  = idx / CDIM;
            int cc = idx - r * CDIM;
            float2 kk = kg[t0 * CDIM + idx];
            float2 vv = vg[t0 * CDIM + idx];
            Kt[r * KSTRIDE + 2 * cc]     = kk.x;
            Kt[r * KSTRIDE + 2 * cc + 1] = kk.y;
            Vt[r * KSTRIDE + 2 * cc]     = vv.x;
            Vt[r * KSTRIDE + 2 * cc + 1] = vv.y;
        }
        __syncthreads();

        for (int r2 = w; r2 < tl; r2 += NWAVE) {
            // broadcast (wave-uniform) vector reads of K row and V row
            float kv[KSTRIDE], vv[KSTRIDE];
            const float4* K4 = (const float4*)&Kt[r2 * KSTRIDE];
            const float4* V4 = (const float4*)&Vt[r2 * KSTRIDE];
#pragma unroll
            for (int i4 = 0; i4 < KSTRIDE / 4; ++i4) {
                ((float4*)kv)[i4] = K4[i4];
                ((float4*)vv)[i4] = V4[i4];
            }
            float sr = 0.f, si = 0.f;
#pragma unroll
            for (int c = 0; c < CDIM; ++c) {
                float kx = kv[2 * c], ky = kv[2 * c + 1];
                sr = fmaf(qre[c], kx, sr);
                sr = fmaf(-qim[c], ky, sr);
                si = fmaf(qre[c], ky, si);
                si = fmaf(qim[c], kx, si);
            }
            float s = sqrtf(fmaf(sr, sr, si * si));
            if (s > m) {
                float alpha = __expf(m - s);     // exp(-inf)=0 covers first iter
                l *= alpha;
#pragma unroll
                for (int c = 0; c < CDIM; ++c) { ar[c] *= alpha; ai[c] *= alpha; }
                m = s;
            }
            float p = __expf(s - m);
            l += p;
#pragma unroll
            for (int c = 0; c < CDIM; ++c) {
                ar[c] = fmaf(p, vv[2 * c], ar[c]);
                ai[c] = fmaf(p, vv[2 * c + 1], ai[c]);
            }
        }
    }

    // ---- merge the 4 per-wave partials per row ----
    __syncthreads();
    if (w > 0) {
        float* dst = &Mbuf[((w - 1) * 64 + lane) * MSTRIDE];
        dst[0] = m; dst[1] = l;
#pragma unroll
        for (int c = 0; c < CDIM; ++c) { dst[2 + 2 * c] = ar[c]; dst[3 + 2 * c] = ai[c]; }
    }
    __syncthreads();
    if (w == 0) {
#pragma unroll
        for (int p = 0; p < NWAVE - 1; ++p) {
            const float* src = &Mbuf[(p * 64 + lane) * MSTRIDE];
            float mp = src[0], lp = src[1];
            float M = fmaxf(m, mp);
            float sa = __expf(m - M), sb = __expf(mp - M);
            l = l * sa + lp * sb;
#pragma unroll
            for (int c = 0; c < CDIM; ++c) {
                ar[c] = ar[c] * sa + src[2 + 2 * c] * sb;
                ai[c] = ai[c] * sa + src[3 + 2 * c] * sb;
            }
            m = M;
        }
        if (writer) {
            float inv = 1.f / l;
#pragma unroll
            for (int c = 0; c < CDIM; ++c)
                outspec[((size_t)(bg * CDIM + c)) * FDIM + f] =
                    make_float2(ar[c] * inv, ai[c] * inv);
        }
    }
}

// ---------------- Kernel 4: irfft(1024) per (b,g,c) ----------------
__global__ void fft_inv(const float2* __restrict__ spec, float* __restrict__ out) {
    __shared__ float re[1024], im[1024];
    const float2* S = spec + (size_t)blockIdx.x * FDIM;
    for (int t = threadIdx.x; t < 1024; t += blockDim.x) {
        int f = (t <= 512) ? t : 1024 - t;
        float2 sv = S[f];
        float sim = (t <= 512) ? sv.y : -sv.y;
        unsigned r = bitrev10(t);
        re[r] = sv.x;
        im[r] = sim;
    }
    __syncthreads();
    for (int s = 0; s < 10; ++s) {
        int half = 1 << s;
        for (int j = threadIdx.x; j < 512; j += blockDim.x) {
            int grp = j >> s;
            int pos = j & (half - 1);
            int i1 = (grp << (s + 1)) + pos;
            int i2 = i1 + half;
            float ang = (float)M_PI * (float)pos / (float)half;   // +sign = inverse
            float sw, cw; __sincosf(ang, &sw, &cw);
            float xr = re[i2], xi = im[i2];
            float tr = cw * xr - sw * xi;
            float ti = cw * xi + sw * xr;
            float ur = re[i1], ui = im[i1];
            re[i1] = ur + tr; im[i1] = ui + ti;
            re[i2] = ur - tr; im[i2] = ui - ti;
        }
        __syncthreads();
    }
    const float scale = 1.0f / 1024.0f;
    for (int t = threadIdx.x; t < 1024; t += blockDim.x)
        out[(size_t)blockIdx.x * TDIM + t] = re[t] * scale;
}

extern "C" void kernel_launch(void* const* d_in, const int* in_sizes, int n_in,
                              void* d_out, int out_size, void* d_ws, size_t ws_size,
                              hipStream_t stream) {
    const float* x  = (const float*)d_in[0];
    const float* wq = (const float*)d_in[1];
    const float* wk = (const float*)d_in[2];
    const float* wv = (const float*)d_in[3];
    float* out = (float*)d_out;

    const size_t n = (size_t)NROW * CDIM;        // 1,067,040 complex per buffer
    float2* xf = (float2*)d_ws;                  // x_fft, later reused as out-spectrum
    float2* q  = xf + n;
    float2* k  = q + n;
    float2* v  = k + n;

    fft_fwd<<<BG * CDIM, 256, 0, stream>>>(x, xf);
    qkv_kernel<<<(NROW * CDIM + 255) / 256, 256, 0, stream>>>(xf, wq, wk, wv, q, k, v);
    attn_kernel<<<BG * NCHUNK, 256, 0, stream>>>(q, k, v, xf /* outspec, aliases xf */);
    fft_inv<<<BG * CDIM, 256, 0, stream>>>(xf, out);
}

// Round 4
// 259.714 us; speedup vs baseline: 2.3925x; 1.0807x over previous
//
#include <hip/hip_runtime.h>
#include <math.h>

// Problem constants
#define BDIM 4
#define GDIM 40
#define CDIM 13
#define TDIM 1024
#define FDIM 513                 // T/2 + 1
#define BG   (BDIM*GDIM)         // 160
#define NROW (BG*FDIM)           // 82080 rows of [13] complex
#define NCHUNK 9                 // 9*64 = 576 >= 513 row-chunks per bg
#define TILE 32                  // f2 rows staged per LDS tile
#define RPW  8                   // rows per wave per tile (TILE/NWAVE)
#define NWAVE 4                  // waves per block; f2 split 4 ways
#define KSTRIDE 28               // floats per LDS tile row (26 padded to 28)
#define MSTRIDE 29               // floats per merge-buffer row

__device__ __forceinline__ unsigned bitrev10(unsigned x) { return __brev(x) >> 22; }

// ---------------- Kernel 1: two-for-one rfft(1024) ----------------
// Block handles signals 2s and 2s+1 as z = x1 + i*x2; separate after FFT.
// out layout: xf[(bg*F + f)*C + c]
__global__ void fft_fwd2(const float* __restrict__ x, float2* __restrict__ xf) {
    __shared__ float re[1024], im[1024];
    const int s2 = blockIdx.x;                   // pair index, 0..1039
    const float* x1 = x + (size_t)(2 * s2) * TDIM;
    const float* x2 = x1 + TDIM;
    for (int t = threadIdx.x; t < 1024; t += blockDim.x) {
        unsigned r = bitrev10(t);
        re[r] = x1[t];
        im[r] = x2[t];
    }
    __syncthreads();
    for (int s = 0; s < 10; ++s) {
        int half = 1 << s;
        for (int j = threadIdx.x; j < 512; j += blockDim.x) {
            int grp = j >> s;
            int pos = j & (half - 1);
            int i1 = (grp << (s + 1)) + pos;
            int i2 = i1 + half;
            float ang = -(float)M_PI * (float)pos / (float)half;
            float sw, cw; __sincosf(ang, &sw, &cw);
            float xr = re[i2], xi = im[i2];
            float tr = cw * xr - sw * xi;
            float ti = cw * xi + sw * xr;
            float ur = re[i1], ui = im[i1];
            re[i1] = ur + tr; im[i1] = ui + ti;
            re[i2] = ur - tr; im[i2] = ui - ti;
        }
        __syncthreads();
    }
    const int sigA = 2 * s2, sigB = sigA + 1;
    const int bgA = sigA / CDIM, cA = sigA % CDIM;
    const int bgB = sigB / CDIM, cB = sigB % CDIM;
    for (int f = threadIdx.x; f < FDIM; f += blockDim.x) {
        int fr = (1024 - f) & 1023;
        float zr = re[f], zi = im[f];
        float wr = re[fr], wi = im[fr];
        // X1 = (Z[f] + conj(Z[N-f]))/2 ; X2 = -i(Z[f] - conj(Z[N-f]))/2
        xf[((size_t)bgA * FDIM + f) * CDIM + cA] =
            make_float2(0.5f * (zr + wr), 0.5f * (zi - wi));
        xf[((size_t)bgB * FDIM + f) * CDIM + cB] =
            make_float2(0.5f * (zi + wi), 0.5f * (wr - zr));
    }
}

// ---------------- Kernel 2: Q/K/V = Xrow @ W (13x13, real weights) ----------------
__global__ void qkv_kernel(const float2* __restrict__ xf,
                           const float* __restrict__ wq,
                           const float* __restrict__ wk,
                           const float* __restrict__ wv,
                           float2* __restrict__ q, float2* __restrict__ k,
                           float2* __restrict__ v) {
    int gid = blockIdx.x * blockDim.x + threadIdx.x;
    if (gid >= NROW * CDIM) return;
    int r = gid / CDIM;
    int i = gid - r * CDIM;
    const float2* xrow = xf + (size_t)r * CDIM;
    float qr = 0, qi = 0, kr = 0, ki = 0, vr = 0, vi = 0;
#pragma unroll
    for (int c = 0; c < CDIM; ++c) {
        float2 xc = xrow[c];
        float a = wq[c * CDIM + i]; qr += xc.x * a; qi += xc.y * a;
        float b = wk[c * CDIM + i]; kr += xc.x * b; ki += xc.y * b;
        float d = wv[c * CDIM + i]; vr += xc.x * d; vi += xc.y * d;
    }
    q[gid] = make_float2(qr, qi);
    k[gid] = make_float2(kr, ki);
    v[gid] = make_float2(vr, vi);
}

// ---------------- Kernel 3: attention ----------------
// Block = 4 waves over 64 Q-rows of one (b,g); lane owns one row. f2 axis split
// across waves in 8-row slices of each 32-row LDS tile. Per tile: phase A
// computes the wave's 8 scores into registers (max tracked), ONE rescale of the
// online-softmax state, phase B does exp + PV. All K/V reads are wave-uniform
// LDS broadcasts. Per-wave partials merged at the end via LDS.
#define CMAC2(c0, kk)                                          \
    sr = fmaf(qre[c0], kk.x, sr); sr = fmaf(-qim[c0], kk.y, sr); \
    si = fmaf(qre[c0], kk.y, si); si = fmaf(qim[c0], kk.x, si);  \
    sr = fmaf(qre[(c0)+1], kk.z, sr); sr = fmaf(-qim[(c0)+1], kk.w, sr); \
    si = fmaf(qre[(c0)+1], kk.w, si); si = fmaf(qim[(c0)+1], kk.z, si);

#define PV2(c0, vv)                                            \
    ar[c0] = fmaf(p, vv.x, ar[c0]); ai[c0] = fmaf(p, vv.y, ai[c0]); \
    ar[(c0)+1] = fmaf(p, vv.z, ar[(c0)+1]); ai[(c0)+1] = fmaf(p, vv.w, ai[(c0)+1]);

__global__ __launch_bounds__(256, 3) void attn_kernel(const float2* __restrict__ q,
                                                      const float2* __restrict__ k,
                                                      const float2* __restrict__ v,
                                                      float2* __restrict__ outspec) {
    __shared__ __align__(16) float Kt[TILE * KSTRIDE];       // 3584 B
    __shared__ __align__(16) float Vt[TILE * KSTRIDE];       // 3584 B
    __shared__ float Mbuf[(NWAVE - 1) * 64 * MSTRIDE];       // 22272 B

    const int bg    = blockIdx.x / NCHUNK;
    const int chunk = blockIdx.x % NCHUNK;
    const int tid   = threadIdx.x;
    const int w     = tid >> 6;
    const int lane  = tid & 63;
    const int frow  = chunk * 64 + lane;
    const bool writer = (frow < FDIM);
    const int f     = writer ? frow : (FDIM - 1);
    const size_t base = (size_t)bg * FDIM * CDIM;

    float qre[CDIM], qim[CDIM];
    {
        const float2* qrow = q + base + (size_t)f * CDIM;
#pragma unroll
        for (int c = 0; c < CDIM; ++c) { float2 t = qrow[c]; qre[c] = t.x; qim[c] = t.y; }
    }

    float ar[CDIM], ai[CDIM];
#pragma unroll
    for (int c = 0; c < CDIM; ++c) { ar[c] = 0.f; ai[c] = 0.f; }
    float m = -INFINITY, l = 0.f;

    const float2* __restrict__ kg = k + base;
    const float2* __restrict__ vg = v + base;

    for (int t0 = 0; t0 < FDIM; t0 += TILE) {
        const int tl = min(TILE, FDIM - t0);
        __syncthreads();                          // previous tile fully consumed
        const int nd2 = tl * CDIM;
        for (int idx = tid; idx < nd2; idx += 256) {
            int r  = idx / CDIM;
            int cc = idx - r * CDIM;
            float2 kk = kg[t0 * CDIM + idx];
            float2 vv = vg[t0 * CDIM + idx];
            Kt[r * KSTRIDE + 2 * cc]     = kk.x;
            Kt[r * KSTRIDE + 2 * cc + 1] = kk.y;
            Vt[r * KSTRIDE + 2 * cc]     = vv.x;
            Vt[r * KSTRIDE + 2 * cc + 1] = vv.y;
        }
        __syncthreads();

        const int r0 = w * RPW;
        float s[RPW];
        float tmax = -INFINITY;
#pragma unroll
        for (int rr = 0; rr < RPW; ++rr) {
            int r2 = r0 + rr;
            if (r2 < tl) {                        // wave-uniform
                const float4* K4 = (const float4*)&Kt[r2 * KSTRIDE];
                float4 k0 = K4[0], k1 = K4[1], k2 = K4[2], k3 = K4[3],
                       k4 = K4[4], k5 = K4[5], k6 = K4[6];
                float sr = 0.f, si = 0.f;
                CMAC2(0, k0) CMAC2(2, k1) CMAC2(4, k2)
                CMAC2(6, k3) CMAC2(8, k4) CMAC2(10, k5)
                sr = fmaf(qre[12], k6.x, sr); sr = fmaf(-qim[12], k6.y, sr);
                si = fmaf(qre[12], k6.y, si); si = fmaf(qim[12], k6.x, si);
                float sv = sqrtf(fmaf(sr, sr, si * si));
                s[rr] = sv;
                tmax = fmaxf(tmax, sv);
            } else {
                s[rr] = -INFINITY;
            }
        }
        if (tmax > m) {                           // at most once per tile
            float alpha = __expf(m - tmax);       // exp(-inf)=0 covers first tile
            l *= alpha;
#pragma unroll
            for (int c = 0; c < CDIM; ++c) { ar[c] *= alpha; ai[c] *= alpha; }
            m = tmax;
        }
#pragma unroll
        for (int rr = 0; rr < RPW; ++rr) {
            int r2 = r0 + rr;
            if (r2 < tl) {
                float p = __expf(s[rr] - m);
                l += p;
                const float4* V4 = (const float4*)&Vt[r2 * KSTRIDE];
                float4 v0 = V4[0], v1 = V4[1], v2 = V4[2], v3 = V4[3],
                       v4 = V4[4], v5 = V4[5], v6 = V4[6];
                PV2(0, v0) PV2(2, v1) PV2(4, v2)
                PV2(6, v3) PV2(8, v4) PV2(10, v5)
                ar[12] = fmaf(p, v6.x, ar[12]); ai[12] = fmaf(p, v6.y, ai[12]);
            }
        }
    }

    // ---- merge the 4 per-wave partials per row ----
    __syncthreads();
    if (w > 0) {
        float* dst = &Mbuf[((w - 1) * 64 + lane) * MSTRIDE];
        dst[0] = m; dst[1] = l;
#pragma unroll
        for (int c = 0; c < CDIM; ++c) { dst[2 + 2 * c] = ar[c]; dst[3 + 2 * c] = ai[c]; }
    }
    __syncthreads();
    if (w == 0) {
#pragma unroll
        for (int p2 = 0; p2 < NWAVE - 1; ++p2) {
            const float* src = &Mbuf[(p2 * 64 + lane) * MSTRIDE];
            float mp = src[0], lp = src[1];
            float M = fmaxf(m, mp);
            float sa = __expf(m - M), sb = __expf(mp - M);
            l = l * sa + lp * sb;
#pragma unroll
            for (int c = 0; c < CDIM; ++c) {
                ar[c] = ar[c] * sa + src[2 + 2 * c] * sb;
                ai[c] = ai[c] * sa + src[3 + 2 * c] * sb;
            }
            m = M;
        }
        if (writer) {
            float inv = 1.f / l;
#pragma unroll
            for (int c = 0; c < CDIM; ++c)
                outspec[((size_t)(bg * CDIM + c)) * FDIM + f] =
                    make_float2(ar[c] * inv, ai[c] * inv);
        }
    }
}

// ---------------- Kernel 4: two-for-one irfft(1024) ----------------
// Rows 2s and 2s+1 of outspec fused: S = Y1h + i*Y2h (Hermitian extensions,
// DC/Nyquist imag zeroed to match irfft semantics); inverse FFT; y1=Re, y2=Im.
__global__ void fft_inv2(const float2* __restrict__ spec, float* __restrict__ out) {
    __shared__ float re[1024], im[1024];
    const int s2 = blockIdx.x;                   // pair 0..1039
    const float2* Y1 = spec + (size_t)(2 * s2) * FDIM;
    const float2* Y2 = Y1 + FDIM;
    for (int t = threadIdx.x; t < 1024; t += blockDim.x) {
        float a, b, c, d;
        if (t <= 512) {
            float2 y1 = Y1[t], y2 = Y2[t];
            bool edge = (t == 0) | (t == 512);
            a = y1.x; b = edge ? 0.f : y1.y;
            c = y2.x; d = edge ? 0.f : y2.y;
        } else {
            float2 y1 = Y1[1024 - t], y2 = Y2[1024 - t];
            a = y1.x; b = -y1.y;
            c = y2.x; d = -y2.y;
        }
        unsigned r = bitrev10(t);
        re[r] = a - d;                            // Re(Y1h + i*Y2h)
        im[r] = b + c;                            // Im(Y1h + i*Y2h)
    }
    __syncthreads();
    for (int s = 0; s < 10; ++s) {
        int half = 1 << s;
        for (int j = threadIdx.x; j < 512; j += blockDim.x) {
            int grp = j >> s;
            int pos = j & (half - 1);
            int i1 = (grp << (s + 1)) + pos;
            int i2 = i1 + half;
            float ang = (float)M_PI * (float)pos / (float)half;   // +sign = inverse
            float sw, cw; __sincosf(ang, &sw, &cw);
            float xr = re[i2], xi = im[i2];
            float tr = cw * xr - sw * xi;
            float ti = cw * xi + sw * xr;
            float ur = re[i1], ui = im[i1];
            re[i1] = ur + tr; im[i1] = ui + ti;
            re[i2] = ur - tr; im[i2] = ui - ti;
        }
        __syncthreads();
    }
    const float scale = 1.0f / 1024.0f;
    float* o1 = out + (size_t)(2 * s2) * TDIM;
    for (int t = threadIdx.x; t < 1024; t += blockDim.x) {
        o1[t]        = re[t] * scale;
        o1[TDIM + t] = im[t] * scale;
    }
}

extern "C" void kernel_launch(void* const* d_in, const int* in_sizes, int n_in,
                              void* d_out, int out_size, void* d_ws, size_t ws_size,
                              hipStream_t stream) {
    const float* x  = (const float*)d_in[0];
    const float* wq = (const float*)d_in[1];
    const float* wk = (const float*)d_in[2];
    const float* wv = (const float*)d_in[3];
    float* out = (float*)d_out;

    const size_t n = (size_t)NROW * CDIM;        // 1,067,040 complex per buffer
    float2* xf = (float2*)d_ws;                  // x_fft, later reused as out-spectrum
    float2* q  = xf + n;
    float2* k  = q + n;
    float2* v  = k + n;

    fft_fwd2<<<BG * CDIM / 2, 256, 0, stream>>>(x, xf);
    qkv_kernel<<<(NROW * CDIM + 255) / 256, 256, 0, stream>>>(xf, wq, wk, wv, q, k, v);
    attn_kernel<<<BG * NCHUNK, 256, 0, stream>>>(q, k, v, xf /* outspec, aliases xf */);
    fft_inv2<<<BG * CDIM / 2, 256, 0, stream>>>(xf, out);
}